// Round 5
// baseline (132.304 us; speedup 1.0000x reference)
//
#include <hip/hip_runtime.h>

#define IMG  512
#define BTX  64            // block threads x
#define BTY  4             // block threads y
#define PXY  4             // pixels per thread in y
#define TW   128           // tile width  = BTX * 2
#define TH   16            // tile height = BTY * PXY
#define HALO 2
#define LWD  (TW + 4)      // 132 data cols
#define LW   136           // padded row stride (even -> b64-aligned everywhere)
#define LH   (TH + 4)      // 20 rows

typedef float v2f __attribute__((ext_vector_type(2)));
typedef int   v2i __attribute__((ext_vector_type(2)));

// q = p * KS2, KS2 = sqrt(50/ln2) * 2^11.5 : intensity term lands directly in
// float exponent-field units (Schraudolph exp2, validated round 4).
#define KS2      24598.990f
#define INV_KS2  4.0652061e-05f

__device__ __forceinline__ int reflect_idx(int g) {
    int a = abs(g);
    return min(a, 2 * IMG - 2 - a);
}

__global__ __launch_bounds__(256) void bilateral_kernel(
    const float* __restrict__ img, float* __restrict__ out)
{
    __shared__ float q[LH][LW];

    const int plane = blockIdx.z;
    const int x0 = blockIdx.x * TW;
    const int y0 = blockIdx.y * TH;
    const float* __restrict__ src = img + (size_t)plane * (IMG * IMG);

    const int tx = threadIdx.x, ty = threadIdx.y;

    // Stage 20 rows x 132 cols, division-free: pass p covers row 4*p + ty.
    #pragma unroll
    for (int p = 0; p < 5; ++p) {
        int r  = 4 * p + ty;
        int gr = reflect_idx(y0 - HALO + r) * IMG;
        q[r][tx]      = src[gr + reflect_idx(x0 - HALO + tx)]      * KS2;
        q[r][tx + 64] = src[gr + reflect_idx(x0 - HALO + tx + 64)] * KS2;
        if (tx < 4)
            q[r][tx + 128] = src[gr + reflect_idx(x0 - HALO + tx + 128)] * KS2;
    }
    __syncthreads();

    // Batched window load: 8 rows x 6 cols into registers, 24x ds_read_b64.
    // One wave = one row (ty uniform) -> 512B contiguous per read, no conflicts.
    float w[PXY + 4][6];
    #pragma unroll
    for (int r = 0; r < PXY + 4; ++r) {
        const float* row = &q[PXY * ty + r][2 * tx];
        v2f a = *reinterpret_cast<const v2f*>(row);
        v2f b = *reinterpret_cast<const v2f*>(row + 2);
        v2f c = *reinterpret_cast<const v2f*>(row + 4);
        w[r][0] = a.x; w[r][1] = a.y;
        w[r][2] = b.x; w[r][3] = b.y;
        w[r][4] = c.x; w[r][5] = c.y;
    }

    v2f res[PXY];
    #pragma unroll
    for (int p = 0; p < PXY; ++p) {
        v2f qc;
        qc.x = w[p + 2][2];
        qc.y = w[p + 2][3];
        v2f wsum = {1.0f, 1.0f};   // center tap exact
        v2f acc  = qc;

        #pragma unroll
        for (int dy = 0; dy < 5; ++dy) {
            #pragma unroll
            for (int dx = 0; dx < 5; ++dx) {
                if (dx == 2 && dy == 2) continue;
                const int r2 = (dx - 2) * (dx - 2) + (dy - 2) * (dy - 2);
                // Ktap = float_bias + 2^23*log2(spatial_w) in exponent units
                const float Ktap = (float)(1065353216.0 - 6051101.63118 * (double)r2);

                v2f qt;
                qt.x = w[p + dy][dx];
                qt.y = w[p + dy][dx + 1];

                v2f d = qt - qc;                          // v_pk_add (neg)
                v2f t = Ktap - d * d;                     // v_pk_fma
                v2i iv = __builtin_convertvector(t, v2i); // 2x v_cvt_i32_f32
                v2f e  = __builtin_bit_cast(v2f, iv);     // bitcast: e ~ 2^arg

                wsum += e;                                // v_pk_add
                acc  += e * qt;                           // v_pk_fma
            }
        }
        res[p].x = acc.x * __builtin_amdgcn_rcpf(wsum.x) * INV_KS2;
        res[p].y = acc.y * __builtin_amdgcn_rcpf(wsum.y) * INV_KS2;
    }

    float* dst = out + (size_t)plane * (IMG * IMG)
                     + (size_t)(y0 + PXY * ty) * IMG + (x0 + 2 * tx);
    #pragma unroll
    for (int p = 0; p < PXY; ++p)
        *reinterpret_cast<v2f*>(dst + p * IMG) = res[p];
}

extern "C" void kernel_launch(void* const* d_in, const int* in_sizes, int n_in,
                              void* d_out, int out_size, void* d_ws, size_t ws_size,
                              hipStream_t stream) {
    const float* img = (const float*)d_in[0];
    float* out = (float*)d_out;
    int planes = in_sizes[0] / (IMG * IMG);  // 48
    dim3 grid(IMG / TW, IMG / TH, planes);   // (4, 32, 48)
    dim3 block(BTX, BTY, 1);
    bilateral_kernel<<<grid, block, 0, stream>>>(img, out);
}